// Round 8
// baseline (686.503 us; speedup 1.0000x reference)
//
#include <hip/hip_runtime.h>

typedef short bf16x8 __attribute__((ext_vector_type(8)));
typedef float f32x4 __attribute__((ext_vector_type(4)));

constexpr int Tc = 2048, Ec = 1024, Hc = 16, Dc = 64;

__device__ __forceinline__ short f2b(float f) {  // fp32 -> bf16 RNE
    unsigned u = __builtin_bit_cast(unsigned, f);
    unsigned r = (u + 0x7FFFu + ((u >> 16) & 1u)) >> 16;
    return (short)r;
}
__device__ __forceinline__ float b2f(short s) {
    unsigned u = ((unsigned)(unsigned short)s) << 16;
    return __builtin_bit_cast(float, u);
}
__device__ __forceinline__ void gll16(const void* g, void* l) {
    // global -> LDS direct, 16B/lane; LDS dest = wave-uniform base + lane*16
    __builtin_amdgcn_global_load_lds(
        (const __attribute__((address_space(1))) unsigned int*)g,
        (__attribute__((address_space(3))) unsigned int*)l, 16, 0, 0);
}

// ---------------------------------------------------------------------------
__global__ __launch_bounds__(256) void convert_f32_bf16(
    const float* __restrict__ in, short* __restrict__ out, int n)
{
    int i = (blockIdx.x * 256 + threadIdx.x) * 4;
    if (i < n) {
        float4 v = *(const float4*)(in + i);
        short4 o;
        o.x = f2b(v.x); o.y = f2b(v.y); o.z = f2b(v.z); o.w = f2b(v.w);
        *(short4*)(out + i) = o;
    }
}

// in [K][N] fp32 -> out [N][K] bf16 (i.e. B^T for the GEMM)
__global__ __launch_bounds__(256) void transpose_conv(
    const float* __restrict__ in, short* __restrict__ out, int K, int N)
{
    __shared__ float t[64][65];
    const int k0 = blockIdx.y * 64, n0 = blockIdx.x * 64;
    const int tid = threadIdx.x;
#pragma unroll
    for (int rep = 0; rep < 16; ++rep) {
        int flat = rep * 256 + tid;
        int r = flat >> 6, c = flat & 63;
        t[r][c] = in[(size_t)(k0 + r) * N + n0 + c];
    }
    __syncthreads();
#pragma unroll
    for (int rep = 0; rep < 16; ++rep) {
        int flat = rep * 256 + tid;
        int r = flat >> 6, c = flat & 63;
        out[(size_t)(n0 + r) * K + k0 + c] = f2b(t[c][r]);
    }
}

// ---------------------------------------------------------------------------
// bf16 GEMM, m97 structure (unchanged this round).
// ---------------------------------------------------------------------------
template <int MODE>
__global__ __launch_bounds__(256) void gemm_bf16(
    const short* __restrict__ A, const short* __restrict__ Bt,
    const float* __restrict__ bias,
    short* __restrict__ Qb, short* __restrict__ Kb, short* __restrict__ Vt,
    float* __restrict__ C, int M, int N, int K)
{
    __shared__ __align__(16) short As[128 * 32];
    __shared__ __align__(16) short Bs[128 * 32];

    const int tid = threadIdx.x;
    const int lane = tid & 63, w = tid >> 6;
    const int l15 = lane & 15, l4 = lane >> 4;
    const int wm = w >> 1, wn = w & 1;
    const int m0 = blockIdx.y * 128, n0 = blockIdx.x * 128;

    f32x4 acc[4][4];
#pragma unroll
    for (int i = 0; i < 4; ++i)
#pragma unroll
        for (int j = 0; j < 4; ++j) acc[i][j] = (f32x4)0.f;

    for (int k0 = 0; k0 < K; k0 += 32) {
        __syncthreads();
#pragma unroll
        for (int i = 0; i < 2; ++i) {
            const int slot = w * 64 + i * 256 + lane;      // 0..511
            const int row = slot >> 2, cb = slot & 3;      // 4x16B per 32-col row
            char* ldst = (char*)As + (w * 64 + i * 256) * 16;  // wave-uniform
            gll16(A + (size_t)(m0 + row) * K + k0 + cb * 8, ldst);
            char* ldst2 = (char*)Bs + (w * 64 + i * 256) * 16;
            gll16(Bt + (size_t)(n0 + row) * K + k0 + cb * 8, ldst2);
        }
        __syncthreads();

        bf16x8 af[4], bfr[4];
#pragma unroll
        for (int f = 0; f < 4; ++f) {
            af[f]  = *(const bf16x8*)((const char*)As + ((wm * 64 + f * 16 + l15) * 32 + l4 * 8) * 2);
            bfr[f] = *(const bf16x8*)((const char*)Bs + ((wn * 64 + f * 16 + l15) * 32 + l4 * 8) * 2);
        }
#pragma unroll
        for (int fm = 0; fm < 4; ++fm)
#pragma unroll
            for (int fn = 0; fn < 4; ++fn)
                acc[fm][fn] = __builtin_amdgcn_mfma_f32_16x16x32_bf16(
                    af[fm], bfr[fn], acc[fm][fn], 0, 0, 0);
    }

    // epilogue: C/D layout col = lane&15, row = (lane>>4)*4 + r
#pragma unroll
    for (int fn = 0; fn < 4; ++fn) {
        const int n = n0 + wn * 64 + fn * 16 + l15;
        const float bv = bias[n];
        if (MODE == 0) {
            const int sel = n >> 10, nq = n & 1023, hh = nq >> 6, dd = nq & 63;
#pragma unroll
            for (int fm = 0; fm < 4; ++fm)
#pragma unroll
                for (int r = 0; r < 4; ++r) {
                    const int mrow = m0 + wm * 64 + fm * 16 + l4 * 4 + r;
                    const short hv = f2b(acc[fm][fn][r] + bv);
                    const int bb = mrow >> 11, tt = mrow & 2047;
                    const size_t bh = (size_t)(bb * Hc + hh);
                    if (sel == 0)      Qb[(bh * Tc + tt) * Dc + dd] = hv;
                    else if (sel == 1) Kb[(bh * Tc + tt) * Dc + dd] = hv;
                    else               Vt[(bh * Dc + dd) * Tc + tt] = hv;
                }
        } else {
#pragma unroll
            for (int fm = 0; fm < 4; ++fm)
#pragma unroll
                for (int r = 0; r < 4; ++r) {
                    const int mrow = m0 + wm * 64 + fm * 16 + l4 * 4 + r;
                    C[(size_t)mrow * N + n] = acc[fm][fn][r] + bv;
                }
        }
    }
}

// ---------------------------------------------------------------------------
// Flash attention v3: NO LDS, NO barriers. K/V per head (256 KB each) is
// L2-resident, so MFMA fragments are read DIRECTLY from global (m169 regime:
// staging L2-fit data is pure overhead). 4 independent waves per block; all
// waves read identical K/V fragment addresses -> L1 catches the 4x reuse.
// Swapped QK^T (S^T = K*Q): lane owns q-row l15 -> per-lane softmax state,
// 4 shuffles/tile. P stays in registers via 8x64b shuffle exchange.
// Swapped PV (O^T = Vt*P^T): alpha-rescale in-lane.
// ---------------------------------------------------------------------------
__global__ __launch_bounds__(256, 4) void attn_direct(
    const short* __restrict__ Qg, const short* __restrict__ Kg,
    const short* __restrict__ Vtg, short* __restrict__ Ab)
{
    const int tid = threadIdx.x;
    const int lane = tid & 63, w = tid >> 6;
    const int l15 = lane & 15, l4 = lane >> 4;
    const int tq = (int)gridDim.x - 1 - (int)blockIdx.x;  // long blocks first
    const int h = blockIdx.y, b = blockIdx.z;
    const size_t base = (size_t)(b * Hc + h) * Tc * Dc;   // same extent Q,K,Vt
    const int q0 = tq * 64 + w * 16;                      // wave's q-rows

    // Q fragments (B-operand of swapped QK): lane holds q-row l15,
    // d = kf*32 + l4*8 .. +8.  Pre-scaled by 1/sqrt(D)=0.125 (exact in bf16).
    bf16x8 qf[2];
    {
        const short* qp = Qg + base + (size_t)(q0 + l15) * Dc + l4 * 8;
        qf[0] = *(const bf16x8*)qp;
        qf[1] = *(const bf16x8*)(qp + 32);
#pragma unroll
        for (int e = 0; e < 8; ++e) {
            qf[0][e] = f2b(b2f(qf[0][e]) * 0.125f);
            qf[1][e] = f2b(b2f(qf[1][e]) * 0.125f);
        }
    }

    f32x4 ot[4];                 // O^T: d = fd*16 + l4*4 + r, q = l15
    float mr = -1e30f, ls = 0.f; // per-lane (q = l15) running stats
#pragma unroll
    for (int i = 0; i < 4; ++i) ot[i] = (f32x4)0.f;

    // shuffle-exchange constants (validated in v2)
    const int srcA = l15 + (((2 * l4) & 3) << 4);
    const int srcB = l15 + (((2 * l4 + 1) & 3) << 4);
    const bool hiFn = ((l4 >> 1) & 1) != 0;

    // per-lane base pointers for fragment gathers
    const short* kpl = Kg + base + (size_t)l15 * Dc + l4 * 8;      // + key*Dc
    const short* vpl = Vtg + base + (size_t)l15 * Tc + l4 * 8;     // + d*Tc + t

    for (int st = 0; st <= tq; ++st) {
        // ---- K fragments direct from global (L2): 8 x dwordx4 ----
        const short* kp = kpl + (size_t)(st * 64) * Dc;
        bf16x8 kb[2][4];
#pragma unroll
        for (int fn = 0; fn < 4; ++fn)
#pragma unroll
            for (int kf = 0; kf < 2; ++kf)
                kb[kf][fn] = *(const bf16x8*)(kp + (size_t)(fn * 16) * Dc + kf * 32);

        // S^T = K·Q : lane holds q=l15, key = fn*16 + l4*4 + r
        f32x4 s[4];
#pragma unroll
        for (int fn = 0; fn < 4; ++fn) s[fn] = (f32x4)0.f;
#pragma unroll
        for (int kf = 0; kf < 2; ++kf)
#pragma unroll
            for (int fn = 0; fn < 4; ++fn)
                s[fn] = __builtin_amdgcn_mfma_f32_16x16x32_bf16(kb[kf][fn], qf[kf], s[fn], 0, 0, 0);

        // ---- V fragments issued now; overlap the softmax below ----
        const short* vp = vpl + st * 64;
        bf16x8 vb[2][4];
#pragma unroll
        for (int fd = 0; fd < 4; ++fd)
#pragma unroll
            for (int kf = 0; kf < 2; ++kf)
                vb[kf][fd] = *(const bf16x8*)(vp + (size_t)(fd * 16) * Tc + kf * 32);

        if (st == tq) {  // causal mask: key > q  (tile-local indices)
#pragma unroll
            for (int fn = 0; fn < 4; ++fn)
#pragma unroll
                for (int r = 0; r < 4; ++r)
                    if (fn * 16 + l4 * 4 + r > w * 16 + l15) s[fn][r] = -1e30f;
        }

        // online softmax, fully per-lane (q = l15); 64 keys over 4 l4-groups
        float tm = -1e30f;
#pragma unroll
        for (int fn = 0; fn < 4; ++fn)
#pragma unroll
            for (int r = 0; r < 4; ++r) tm = fmaxf(tm, s[fn][r]);
        tm = fmaxf(tm, __shfl_xor(tm, 16));
        tm = fmaxf(tm, __shfl_xor(tm, 32));
        const float mn = fmaxf(mr, tm);
        const float alpha = __expf(mr - mn);
        mr = mn;
        float rs = 0.f;
#pragma unroll
        for (int fn = 0; fn < 4; ++fn)
#pragma unroll
            for (int r = 0; r < 4; ++r) {
                const float p = __expf(s[fn][r] - mn);
                s[fn][r] = p;
                rs += p;
            }
        rs += __shfl_xor(rs, 16);
        rs += __shfl_xor(rs, 32);
        ls = ls * alpha + rs;

        // pack P to bf16 quads: plo[fn] = [r0 r1 r2 r3] for q=l15
        unsigned long long plo[4];
#pragma unroll
        for (int fn = 0; fn < 4; ++fn) {
            unsigned lo = (unsigned)(unsigned short)f2b(s[fn][0]) |
                          ((unsigned)(unsigned short)f2b(s[fn][1]) << 16);
            unsigned hi = (unsigned)(unsigned short)f2b(s[fn][2]) |
                          ((unsigned)(unsigned short)f2b(s[fn][3]) << 16);
            plo[fn] = (unsigned long long)lo | ((unsigned long long)hi << 32);
        }

        // build PV B-fragments by shuffle exchange:
        // pb[kf] elem e <-> key k = kf*32 + l4*8 + e
        bf16x8 pb[2];
#pragma unroll
        for (int kf = 0; kf < 2; ++kf) {
            unsigned long long a0 = __shfl(plo[kf * 2],     srcA, 64);
            unsigned long long a1 = __shfl(plo[kf * 2 + 1], srcA, 64);
            unsigned long long b0 = __shfl(plo[kf * 2],     srcB, 64);
            unsigned long long b1 = __shfl(plo[kf * 2 + 1], srcB, 64);
            union { unsigned long long u[2]; bf16x8 v; } cvt;
            cvt.u[0] = hiFn ? a1 : a0;
            cvt.u[1] = hiFn ? b1 : b0;
            pb[kf] = cvt.v;
        }

        // rescale O^T (in-lane) then O^T += Vt · P^T
#pragma unroll
        for (int fd = 0; fd < 4; ++fd)
#pragma unroll
            for (int r = 0; r < 4; ++r) ot[fd][r] *= alpha;
#pragma unroll
        for (int kf = 0; kf < 2; ++kf)
#pragma unroll
            for (int fd = 0; fd < 4; ++fd)
                ot[fd] = __builtin_amdgcn_mfma_f32_16x16x32_bf16(vb[kf][fd], pb[kf], ot[fd], 0, 0, 0);
    }

    // normalize + store: row q = q0 + l15, cols d = fd*16 + l4*4 + 0..3
    const float inv = 1.f / ls;
    const size_t rowb = (size_t)(b * Tc + q0 + l15) * Ec + h * Dc;
#pragma unroll
    for (int fd = 0; fd < 4; ++fd) {
        short4 r4;
        r4.x = f2b(ot[fd][0] * inv);
        r4.y = f2b(ot[fd][1] * inv);
        r4.z = f2b(ot[fd][2] * inv);
        r4.w = f2b(ot[fd][3] * inv);
        *(short4*)(Ab + rowb + fd * 16 + l4 * 4) = r4;
    }
}

// ---------------------------------------------------------------------------
extern "C" void kernel_launch(void* const* d_in, const int* in_sizes, int n_in,
                              void* d_out, int out_size, void* d_ws, size_t ws_size,
                              hipStream_t stream)
{
    const float* x     = (const float*)d_in[0];
    const float* w_qkv = (const float*)d_in[1];
    const float* b_qkv = (const float*)d_in[2];
    const float* w_out = (const float*)d_in[3];
    const float* b_out = (const float*)d_in[4];
    float* out = (float*)d_out;

    const size_t NX = (size_t)8192 * 1024;
    short* xb  = (short*)d_ws;        // 16 MB
    short* Wtq = xb + NX;             // [3072][1024] bf16
    short* Wto = Wtq + (size_t)3072 * 1024;  // [1024][1024] bf16
    short* Qb  = Wto + (size_t)1024 * 1024;  // [B,H,T,D] bf16
    short* Kb  = Qb + NX;
    short* Vt  = Kb + NX;             // [B,H,D,T] bf16
    short* Ab  = Vt + NX;             // [B*T][E] bf16

    convert_f32_bf16<<<8192, 256, 0, stream>>>(x, xb, (int)NX);
    transpose_conv<<<dim3(48, 16), 256, 0, stream>>>(w_qkv, Wtq, 1024, 3072);
    transpose_conv<<<dim3(16, 16), 256, 0, stream>>>(w_out, Wto, 1024, 1024);

    gemm_bf16<0><<<dim3(24, 64), 256, 0, stream>>>(
        xb, Wtq, b_qkv, Qb, Kb, Vt, nullptr, 8192, 3072, 1024);

    attn_direct<<<dim3(32, 16, 4), 256, 0, stream>>>(Qb, Kb, Vt, Ab);

    gemm_bf16<1><<<dim3(8, 64), 256, 0, stream>>>(
        Ab, Wto, b_out, nullptr, nullptr, nullptr, out, 8192, 1024, 1024);
}

// Round 9
// 408.942 us; speedup vs baseline: 1.6787x; 1.6787x over previous
//
#include <hip/hip_runtime.h>

typedef short bf16x8 __attribute__((ext_vector_type(8)));
typedef float f32x4 __attribute__((ext_vector_type(4)));

constexpr int Tc = 2048, Ec = 1024, Hc = 16, Dc = 64;

__device__ __forceinline__ short f2b(float f) {  // fp32 -> bf16 RNE
    unsigned u = __builtin_bit_cast(unsigned, f);
    unsigned r = (u + 0x7FFFu + ((u >> 16) & 1u)) >> 16;
    return (short)r;
}
__device__ __forceinline__ float b2f(short s) {
    unsigned u = ((unsigned)(unsigned short)s) << 16;
    return __builtin_bit_cast(float, u);
}
__device__ __forceinline__ void gll16(const void* g, void* l) {
    // global -> LDS direct, 16B/lane; LDS dest = wave-uniform base + lane*16
    __builtin_amdgcn_global_load_lds(
        (const __attribute__((address_space(1))) unsigned int*)g,
        (__attribute__((address_space(3))) unsigned int*)l, 16, 0, 0);
}

// ---------------------------------------------------------------------------
__global__ __launch_bounds__(256) void convert_f32_bf16(
    const float* __restrict__ in, short* __restrict__ out, int n)
{
    int i = (blockIdx.x * 256 + threadIdx.x) * 4;
    if (i < n) {
        float4 v = *(const float4*)(in + i);
        short4 o;
        o.x = f2b(v.x); o.y = f2b(v.y); o.z = f2b(v.z); o.w = f2b(v.w);
        *(short4*)(out + i) = o;
    }
}

// in [K][N] fp32 -> out [N][K] bf16 (i.e. B^T for the GEMM)
__global__ __launch_bounds__(256) void transpose_conv(
    const float* __restrict__ in, short* __restrict__ out, int K, int N)
{
    __shared__ float t[64][65];
    const int k0 = blockIdx.y * 64, n0 = blockIdx.x * 64;
    const int tid = threadIdx.x;
#pragma unroll
    for (int rep = 0; rep < 16; ++rep) {
        int flat = rep * 256 + tid;
        int r = flat >> 6, c = flat & 63;
        t[r][c] = in[(size_t)(k0 + r) * N + n0 + c];
    }
    __syncthreads();
#pragma unroll
    for (int rep = 0; rep < 16; ++rep) {
        int flat = rep * 256 + tid;
        int r = flat >> 6, c = flat & 63;
        out[(size_t)(n0 + r) * K + k0 + c] = f2b(t[c][r]);
    }
}

// ---------------------------------------------------------------------------
// bf16 GEMM, m97 structure (unchanged this round).
// ---------------------------------------------------------------------------
template <int MODE>
__global__ __launch_bounds__(256) void gemm_bf16(
    const short* __restrict__ A, const short* __restrict__ Bt,
    const float* __restrict__ bias,
    short* __restrict__ Qb, short* __restrict__ Kb, short* __restrict__ Vt,
    float* __restrict__ C, int M, int N, int K)
{
    __shared__ __align__(16) short As[128 * 32];
    __shared__ __align__(16) short Bs[128 * 32];

    const int tid = threadIdx.x;
    const int lane = tid & 63, w = tid >> 6;
    const int l15 = lane & 15, l4 = lane >> 4;
    const int wm = w >> 1, wn = w & 1;
    const int m0 = blockIdx.y * 128, n0 = blockIdx.x * 128;

    f32x4 acc[4][4];
#pragma unroll
    for (int i = 0; i < 4; ++i)
#pragma unroll
        for (int j = 0; j < 4; ++j) acc[i][j] = (f32x4)0.f;

    for (int k0 = 0; k0 < K; k0 += 32) {
        __syncthreads();
#pragma unroll
        for (int i = 0; i < 2; ++i) {
            const int slot = w * 64 + i * 256 + lane;      // 0..511
            const int row = slot >> 2, cb = slot & 3;      // 4x16B per 32-col row
            char* ldst = (char*)As + (w * 64 + i * 256) * 16;  // wave-uniform
            gll16(A + (size_t)(m0 + row) * K + k0 + cb * 8, ldst);
            char* ldst2 = (char*)Bs + (w * 64 + i * 256) * 16;
            gll16(Bt + (size_t)(n0 + row) * K + k0 + cb * 8, ldst2);
        }
        __syncthreads();

        bf16x8 af[4], bfr[4];
#pragma unroll
        for (int f = 0; f < 4; ++f) {
            af[f]  = *(const bf16x8*)((const char*)As + ((wm * 64 + f * 16 + l15) * 32 + l4 * 8) * 2);
            bfr[f] = *(const bf16x8*)((const char*)Bs + ((wn * 64 + f * 16 + l15) * 32 + l4 * 8) * 2);
        }
#pragma unroll
        for (int fm = 0; fm < 4; ++fm)
#pragma unroll
            for (int fn = 0; fn < 4; ++fn)
                acc[fm][fn] = __builtin_amdgcn_mfma_f32_16x16x32_bf16(
                    af[fm], bfr[fn], acc[fm][fn], 0, 0, 0);
    }

    // epilogue: C/D layout col = lane&15, row = (lane>>4)*4 + r
#pragma unroll
    for (int fn = 0; fn < 4; ++fn) {
        const int n = n0 + wn * 64 + fn * 16 + l15;
        const float bv = bias[n];
        if (MODE == 0) {
            const int sel = n >> 10, nq = n & 1023, hh = nq >> 6, dd = nq & 63;
#pragma unroll
            for (int fm = 0; fm < 4; ++fm)
#pragma unroll
                for (int r = 0; r < 4; ++r) {
                    const int mrow = m0 + wm * 64 + fm * 16 + l4 * 4 + r;
                    const short hv = f2b(acc[fm][fn][r] + bv);
                    const int bb = mrow >> 11, tt = mrow & 2047;
                    const size_t bh = (size_t)(bb * Hc + hh);
                    if (sel == 0)      Qb[(bh * Tc + tt) * Dc + dd] = hv;
                    else if (sel == 1) Kb[(bh * Tc + tt) * Dc + dd] = hv;
                    else               Vt[(bh * Dc + dd) * Tc + tt] = hv;
                }
        } else {
#pragma unroll
            for (int fm = 0; fm < 4; ++fm)
#pragma unroll
                for (int r = 0; r < 4; ++r) {
                    const int mrow = m0 + wm * 64 + fm * 16 + l4 * 4 + r;
                    C[(size_t)mrow * N + n] = acc[fm][fn][r] + bv;
                }
        }
    }
}

// ---------------------------------------------------------------------------
// Flash attention v4: v2's validated LDS-staged structure (async DMA staging,
// double buffer, swizzled K/V, swapped-operand softmax, register-P shuffle
// exchange) with Q-TILE PER WAVE DOUBLED to 32 rows (block = 128 q-rows).
// Halves tile-visits (serialization cost) and staging traffic; K/V LDS
// fragment reads amortized over 2 q-groups (32 MFMA per tile-visit).
// ---------------------------------------------------------------------------
__global__ __launch_bounds__(256) void attn_mfma4(
    const short* __restrict__ Qg, const short* __restrict__ Kg,
    const short* __restrict__ Vtg, short* __restrict__ Ab)
{
    __shared__ __align__(16) short Ks[2][64 * 64];
    __shared__ __align__(16) short Vs[2][64 * 64];   // Vt tile: rows d, cols s

    const int tid = threadIdx.x;
    const int lane = tid & 63, w = tid >> 6;
    const int l15 = lane & 15, l4 = lane >> 4;
    const int tqB = (int)gridDim.x - 1 - (int)blockIdx.x;  // long blocks first
    const int h = blockIdx.y, b = blockIdx.z;
    const size_t base = (size_t)(b * Hc + h) * Tc * Dc;    // same extent Q,K,Vt
    const int q0w = tqB * 128 + w * 32;                    // wave's 32 q-rows
    const int NT = 2 * tqB + 2;                            // kv tiles of 64

    // Q fragments (B-operand of swapped QK): group g, lane holds q-row
    // q0w + g*16 + l15, d = kf*32 + l4*8..+8. Pre-scaled by 1/8 (exact bf16).
    bf16x8 qf[2][2];
#pragma unroll
    for (int g = 0; g < 2; ++g) {
        const short* qp = Qg + base + (size_t)(q0w + g * 16 + l15) * Dc + l4 * 8;
        qf[g][0] = *(const bf16x8*)qp;
        qf[g][1] = *(const bf16x8*)(qp + 32);
#pragma unroll
        for (int e = 0; e < 8; ++e) {
            qf[g][0][e] = f2b(b2f(qf[g][0][e]) * 0.125f);
            qf[g][1][e] = f2b(b2f(qf[g][1][e]) * 0.125f);
        }
    }

    f32x4 ot[2][4];                      // O^T per group
    float mr[2] = {-1e30f, -1e30f}, ls[2] = {0.f, 0.f};
#pragma unroll
    for (int g = 0; g < 2; ++g)
#pragma unroll
        for (int i = 0; i < 4; ++i) ot[g][i] = (f32x4)0.f;

    // shuffle-exchange constants (validated in v2)
    const int srcA = l15 + (((2 * l4) & 3) << 4);
    const int srcB = l15 + (((2 * l4 + 1) & 3) << 4);
    const bool hiFn = ((l4 >> 1) & 1) != 0;

    // prologue: stage tile 0 into buffer 0
#pragma unroll
    for (int i = 0; i < 2; ++i) {
        const int slot = w * 64 + i * 256 + lane;
        const int row = slot >> 3, cb = slot & 7;
        const int cbs = cb ^ (row & 7);               // pre-swizzled source
        gll16(Kg + base + (size_t)row * Dc + cbs * 8,
              (char*)&Ks[0][0] + (w * 64 + i * 256) * 16);
        gll16(Vtg + base + (size_t)row * Tc + cbs * 8,
              (char*)&Vs[0][0] + (w * 64 + i * 256) * 16);
    }
    asm volatile("s_waitcnt vmcnt(0)" ::: "memory");
    __syncthreads();

    for (int st = 0; st < NT; ++st) {
        const int cur = st & 1;
        if (st < NT - 1) {  // prefetch next tile into the other buffer
            const int nx = cur ^ 1;
#pragma unroll
            for (int i = 0; i < 2; ++i) {
                const int slot = w * 64 + i * 256 + lane;
                const int row = slot >> 3, cb = slot & 7;
                const int cbs = cb ^ (row & 7);
                gll16(Kg + base + (size_t)((st + 1) * 64 + row) * Dc + cbs * 8,
                      (char*)&Ks[nx][0] + (w * 64 + i * 256) * 16);
                gll16(Vtg + base + (size_t)row * Tc + (st + 1) * 64 + cbs * 8,
                      (char*)&Vs[nx][0] + (w * 64 + i * 256) * 16);
            }
        }

        const char* Kc = (const char*)&Ks[cur][0];
        const char* Vc = (const char*)&Vs[cur][0];

        // K fragments read ONCE, used by both q-groups
        f32x4 s[2][4];
#pragma unroll
        for (int g = 0; g < 2; ++g)
#pragma unroll
            for (int fn = 0; fn < 4; ++fn) s[g][fn] = (f32x4)0.f;
#pragma unroll
        for (int kf = 0; kf < 2; ++kf)
#pragma unroll
            for (int fn = 0; fn < 4; ++fn) {
                const int srow = fn * 16 + l15;   // key row in K tile
                bf16x8 kb = *(const bf16x8*)(Kc + srow * 128 +
                                             ((kf * 64 + l4 * 16) ^ ((srow & 7) << 4)));
#pragma unroll
                for (int g = 0; g < 2; ++g)
                    s[g][fn] = __builtin_amdgcn_mfma_f32_16x16x32_bf16(
                        kb, qf[g][kf], s[g][fn], 0, 0, 0);
            }

        if (st >= NT - 2) {  // diagonal region: causal mask, tile-local
            const int koff = (st - 2 * tqB) * 64;
#pragma unroll
            for (int g = 0; g < 2; ++g)
#pragma unroll
                for (int fn = 0; fn < 4; ++fn)
#pragma unroll
                    for (int r = 0; r < 4; ++r)
                        if (koff + fn * 16 + l4 * 4 + r > w * 32 + g * 16 + l15)
                            s[g][fn][r] = -1e30f;
        }

        // online softmax per group, fully per-lane; pack P, build PV B-frags
        bf16x8 pb[2][2];
        float alpha[2];
#pragma unroll
        for (int g = 0; g < 2; ++g) {
            float tm = -1e30f;
#pragma unroll
            for (int fn = 0; fn < 4; ++fn)
#pragma unroll
                for (int r = 0; r < 4; ++r) tm = fmaxf(tm, s[g][fn][r]);
            tm = fmaxf(tm, __shfl_xor(tm, 16));
            tm = fmaxf(tm, __shfl_xor(tm, 32));
            const float mn = fmaxf(mr[g], tm);
            alpha[g] = __expf(mr[g] - mn);
            mr[g] = mn;
            float rs = 0.f;
#pragma unroll
            for (int fn = 0; fn < 4; ++fn)
#pragma unroll
                for (int r = 0; r < 4; ++r) {
                    const float p = __expf(s[g][fn][r] - mn);
                    s[g][fn][r] = p;
                    rs += p;
                }
            rs += __shfl_xor(rs, 16);
            rs += __shfl_xor(rs, 32);
            ls[g] = ls[g] * alpha[g] + rs;

            unsigned long long plo[4];
#pragma unroll
            for (int fn = 0; fn < 4; ++fn) {
                unsigned lo = (unsigned)(unsigned short)f2b(s[g][fn][0]) |
                              ((unsigned)(unsigned short)f2b(s[g][fn][1]) << 16);
                unsigned hi = (unsigned)(unsigned short)f2b(s[g][fn][2]) |
                              ((unsigned)(unsigned short)f2b(s[g][fn][3]) << 16);
                plo[fn] = (unsigned long long)lo | ((unsigned long long)hi << 32);
            }
#pragma unroll
            for (int kf = 0; kf < 2; ++kf) {
                unsigned long long a0 = __shfl(plo[kf * 2],     srcA, 64);
                unsigned long long a1 = __shfl(plo[kf * 2 + 1], srcA, 64);
                unsigned long long b0 = __shfl(plo[kf * 2],     srcB, 64);
                unsigned long long b1 = __shfl(plo[kf * 2 + 1], srcB, 64);
                union { unsigned long long u[2]; bf16x8 v; } cvt;
                cvt.u[0] = hiFn ? a1 : a0;
                cvt.u[1] = hiFn ? b1 : b0;
                pb[g][kf] = cvt.v;
            }
#pragma unroll
            for (int fd = 0; fd < 4; ++fd)
#pragma unroll
                for (int r = 0; r < 4; ++r) ot[g][fd][r] *= alpha[g];
        }

        // V fragments read ONCE, used by both q-groups: O^T += Vt · P^T
#pragma unroll
        for (int kf = 0; kf < 2; ++kf)
#pragma unroll
            for (int fd = 0; fd < 4; ++fd) {
                const int vrow = fd * 16 + l15;   // d row in Vt tile
                bf16x8 vb = *(const bf16x8*)(Vc + vrow * 128 +
                                             ((kf * 64 + l4 * 16) ^ ((vrow & 7) << 4)));
#pragma unroll
                for (int g = 0; g < 2; ++g)
                    ot[g][fd] = __builtin_amdgcn_mfma_f32_16x16x32_bf16(
                        vb, pb[g][kf], ot[g][fd], 0, 0, 0);
            }

        if (st < NT - 1) {
            asm volatile("s_waitcnt vmcnt(0)" ::: "memory");
            __syncthreads();
        }
    }

    // normalize + store: per group, row q = q0w + g*16 + l15
#pragma unroll
    for (int g = 0; g < 2; ++g) {
        const float inv = 1.f / ls[g];
        const size_t rowb = (size_t)(b * Tc + q0w + g * 16 + l15) * Ec + h * Dc;
#pragma unroll
        for (int fd = 0; fd < 4; ++fd) {
            short4 r4;
            r4.x = f2b(ot[g][fd][0] * inv);
            r4.y = f2b(ot[g][fd][1] * inv);
            r4.z = f2b(ot[g][fd][2] * inv);
            r4.w = f2b(ot[g][fd][3] * inv);
            *(short4*)(Ab + rowb + fd * 16 + l4 * 4) = r4;
        }
    }
}

// ---------------------------------------------------------------------------
extern "C" void kernel_launch(void* const* d_in, const int* in_sizes, int n_in,
                              void* d_out, int out_size, void* d_ws, size_t ws_size,
                              hipStream_t stream)
{
    const float* x     = (const float*)d_in[0];
    const float* w_qkv = (const float*)d_in[1];
    const float* b_qkv = (const float*)d_in[2];
    const float* w_out = (const float*)d_in[3];
    const float* b_out = (const float*)d_in[4];
    float* out = (float*)d_out;

    const size_t NX = (size_t)8192 * 1024;
    short* xb  = (short*)d_ws;        // 16 MB
    short* Wtq = xb + NX;             // [3072][1024] bf16
    short* Wto = Wtq + (size_t)3072 * 1024;  // [1024][1024] bf16
    short* Qb  = Wto + (size_t)1024 * 1024;  // [B,H,T,D] bf16
    short* Kb  = Qb + NX;
    short* Vt  = Kb + NX;             // [B,H,D,T] bf16
    short* Ab  = Vt + NX;             // [B*T][E] bf16

    convert_f32_bf16<<<8192, 256, 0, stream>>>(x, xb, (int)NX);
    transpose_conv<<<dim3(48, 16), 256, 0, stream>>>(w_qkv, Wtq, 1024, 3072);
    transpose_conv<<<dim3(16, 16), 256, 0, stream>>>(w_out, Wto, 1024, 1024);

    gemm_bf16<0><<<dim3(24, 64), 256, 0, stream>>>(
        xb, Wtq, b_qkv, Qb, Kb, Vt, nullptr, 8192, 3072, 1024);

    attn_mfma4<<<dim3(16, 16, 4), 256, 0, stream>>>(Qb, Kb, Vt, Ab);

    gemm_bf16<1><<<dim3(8, 64), 256, 0, stream>>>(
        Ab, Wto, b_out, nullptr, nullptr, nullptr, out, 8192, 1024, 1024);
}

// Round 10
// 316.632 us; speedup vs baseline: 2.1681x; 1.2915x over previous
//
#include <hip/hip_runtime.h>

typedef short bf16x8 __attribute__((ext_vector_type(8)));
typedef float f32x4 __attribute__((ext_vector_type(4)));

constexpr int Tc = 2048, Ec = 1024, Hc = 16, Dc = 64;

__device__ __forceinline__ short f2b(float f) {  // fp32 -> bf16 RNE
    unsigned u = __builtin_bit_cast(unsigned, f);
    unsigned r = (u + 0x7FFFu + ((u >> 16) & 1u)) >> 16;
    return (short)r;
}
__device__ __forceinline__ float b2f(short s) {
    unsigned u = ((unsigned)(unsigned short)s) << 16;
    return __builtin_bit_cast(float, u);
}
__device__ __forceinline__ void gll16(const void* g, void* l) {
    // global -> LDS direct, 16B/lane; LDS dest = wave-uniform base + lane*16
    __builtin_amdgcn_global_load_lds(
        (const __attribute__((address_space(1))) unsigned int*)g,
        (__attribute__((address_space(3))) unsigned int*)l, 16, 0, 0);
}

// ---------------------------------------------------------------------------
__global__ __launch_bounds__(256) void convert_f32_bf16(
    const float* __restrict__ in, short* __restrict__ out, int n)
{
    int i = (blockIdx.x * 256 + threadIdx.x) * 4;
    if (i < n) {
        float4 v = *(const float4*)(in + i);
        short4 o;
        o.x = f2b(v.x); o.y = f2b(v.y); o.z = f2b(v.z); o.w = f2b(v.w);
        *(short4*)(out + i) = o;
    }
}

// in [K][N] fp32 -> out [N][K] bf16 (i.e. B^T for the GEMM)
__global__ __launch_bounds__(256) void transpose_conv(
    const float* __restrict__ in, short* __restrict__ out, int K, int N)
{
    __shared__ float t[64][65];
    const int k0 = blockIdx.y * 64, n0 = blockIdx.x * 64;
    const int tid = threadIdx.x;
#pragma unroll
    for (int rep = 0; rep < 16; ++rep) {
        int flat = rep * 256 + tid;
        int r = flat >> 6, c = flat & 63;
        t[r][c] = in[(size_t)(k0 + r) * N + n0 + c];
    }
    __syncthreads();
#pragma unroll
    for (int rep = 0; rep < 16; ++rep) {
        int flat = rep * 256 + tid;
        int r = flat >> 6, c = flat & 63;
        out[(size_t)(n0 + r) * K + k0 + c] = f2b(t[c][r]);
    }
}

// ---------------------------------------------------------------------------
// bf16 GEMM, m97 structure (unchanged this round).
// ---------------------------------------------------------------------------
template <int MODE>
__global__ __launch_bounds__(256) void gemm_bf16(
    const short* __restrict__ A, const short* __restrict__ Bt,
    const float* __restrict__ bias,
    short* __restrict__ Qb, short* __restrict__ Kb, short* __restrict__ Vt,
    float* __restrict__ C, int M, int N, int K)
{
    __shared__ __align__(16) short As[128 * 32];
    __shared__ __align__(16) short Bs[128 * 32];

    const int tid = threadIdx.x;
    const int lane = tid & 63, w = tid >> 6;
    const int l15 = lane & 15, l4 = lane >> 4;
    const int wm = w >> 1, wn = w & 1;
    const int m0 = blockIdx.y * 128, n0 = blockIdx.x * 128;

    f32x4 acc[4][4];
#pragma unroll
    for (int i = 0; i < 4; ++i)
#pragma unroll
        for (int j = 0; j < 4; ++j) acc[i][j] = (f32x4)0.f;

    for (int k0 = 0; k0 < K; k0 += 32) {
        __syncthreads();
#pragma unroll
        for (int i = 0; i < 2; ++i) {
            const int slot = w * 64 + i * 256 + lane;      // 0..511
            const int row = slot >> 2, cb = slot & 3;      // 4x16B per 32-col row
            char* ldst = (char*)As + (w * 64 + i * 256) * 16;  // wave-uniform
            gll16(A + (size_t)(m0 + row) * K + k0 + cb * 8, ldst);
            char* ldst2 = (char*)Bs + (w * 64 + i * 256) * 16;
            gll16(Bt + (size_t)(n0 + row) * K + k0 + cb * 8, ldst2);
        }
        __syncthreads();

        bf16x8 af[4], bfr[4];
#pragma unroll
        for (int f = 0; f < 4; ++f) {
            af[f]  = *(const bf16x8*)((const char*)As + ((wm * 64 + f * 16 + l15) * 32 + l4 * 8) * 2);
            bfr[f] = *(const bf16x8*)((const char*)Bs + ((wn * 64 + f * 16 + l15) * 32 + l4 * 8) * 2);
        }
#pragma unroll
        for (int fm = 0; fm < 4; ++fm)
#pragma unroll
            for (int fn = 0; fn < 4; ++fn)
                acc[fm][fn] = __builtin_amdgcn_mfma_f32_16x16x32_bf16(
                    af[fm], bfr[fn], acc[fm][fn], 0, 0, 0);
    }

    // epilogue: C/D layout col = lane&15, row = (lane>>4)*4 + r
#pragma unroll
    for (int fn = 0; fn < 4; ++fn) {
        const int n = n0 + wn * 64 + fn * 16 + l15;
        const float bv = bias[n];
        if (MODE == 0) {
            const int sel = n >> 10, nq = n & 1023, hh = nq >> 6, dd = nq & 63;
#pragma unroll
            for (int fm = 0; fm < 4; ++fm)
#pragma unroll
                for (int r = 0; r < 4; ++r) {
                    const int mrow = m0 + wm * 64 + fm * 16 + l4 * 4 + r;
                    const short hv = f2b(acc[fm][fn][r] + bv);
                    const int bb = mrow >> 11, tt = mrow & 2047;
                    const size_t bh = (size_t)(bb * Hc + hh);
                    if (sel == 0)      Qb[(bh * Tc + tt) * Dc + dd] = hv;
                    else if (sel == 1) Kb[(bh * Tc + tt) * Dc + dd] = hv;
                    else               Vt[(bh * Dc + dd) * Tc + tt] = hv;
                }
        } else {
#pragma unroll
            for (int fm = 0; fm < 4; ++fm)
#pragma unroll
                for (int r = 0; r < 4; ++r) {
                    const int mrow = m0 + wm * 64 + fm * 16 + l4 * 4 + r;
                    C[(size_t)mrow * N + n] = acc[fm][fn][r] + bv;
                }
        }
    }
}

// ---------------------------------------------------------------------------
// Flash attention v5 = v2's validated structure (KVBLK=64, 16 q-rows/wave,
// LDS double-buffer via global_load_lds, swizzled K/V, swapped-operand
// softmax, register-P shuffle exchange) + catalog techniques:
//  - exp2-space softmax: Q prescaled by 0.125*log2(e); v_exp_f32 direct
//  - T12: P pack via v_cvt_pk_bf16_f32 (1 instr / 2 values, was ~4/value)
//  - T13: defer-max (THR=8): skip alpha-rescale when max doesn't grow
//  - T5: s_setprio(1) around MFMA clusters (attn +4-7%, m191)
//  - 1-D long-first grid: all 64 longest blocks dispatch first (tail fix)
// ---------------------------------------------------------------------------
__global__ __launch_bounds__(256) void attn_mfma5(
    const short* __restrict__ Qg, const short* __restrict__ Kg,
    const short* __restrict__ Vtg, short* __restrict__ Ab)
{
    __shared__ __align__(16) short Ks[2][64 * 64];
    __shared__ __align__(16) short Vs[2][64 * 64];   // Vt tile: rows d, cols s

    const int tid = threadIdx.x;
    const int lane = tid & 63, w = tid >> 6;
    const int l15 = lane & 15, l4 = lane >> 4;
    const int bid = blockIdx.x;                 // 0..2047, long-first
    const int tq = 31 - (bid >> 6);
    const int hb = bid & 63;
    const int h = hb & 15, b = hb >> 4;
    const size_t base = (size_t)(b * Hc + h) * Tc * Dc;   // same extent Q,K,Vt
    const int q0 = tq * 64 + w * 16;                      // wave's q-rows

    // Q fragments (B-operand of swapped QK): lane holds q-row l15,
    // d = kf*32 + l4*8..+8. Prescale 0.125*log2e -> scores in log2 space.
    const float qscale = 0.125f * 1.44269504088896f;
    bf16x8 qf[2];
    {
        const short* qp = Qg + base + (size_t)(q0 + l15) * Dc + l4 * 8;
        qf[0] = *(const bf16x8*)qp;
        qf[1] = *(const bf16x8*)(qp + 32);
#pragma unroll
        for (int e = 0; e < 8; ++e) {
            qf[0][e] = f2b(b2f(qf[0][e]) * qscale);
            qf[1][e] = f2b(b2f(qf[1][e]) * qscale);
        }
    }

    f32x4 ot[4];                 // O^T: d = fd*16 + l4*4 + r, q = l15
    float mr = -1e30f, ls = 0.f; // per-lane (q = l15) running stats
#pragma unroll
    for (int i = 0; i < 4; ++i) ot[i] = (f32x4)0.f;

    // shuffle-exchange constants (validated in v2)
    const int srcA = l15 + (((2 * l4) & 3) << 4);
    const int srcB = l15 + (((2 * l4 + 1) & 3) << 4);
    const bool hiFn = ((l4 >> 1) & 1) != 0;

    // prologue: stage tile 0 into buffer 0
#pragma unroll
    for (int i = 0; i < 2; ++i) {
        const int slot = w * 64 + i * 256 + lane;
        const int row = slot >> 3, cb = slot & 7;
        const int cbs = cb ^ (row & 7);               // pre-swizzled source
        gll16(Kg + base + (size_t)row * Dc + cbs * 8,
              (char*)&Ks[0][0] + (w * 64 + i * 256) * 16);
        gll16(Vtg + base + (size_t)row * Tc + cbs * 8,
              (char*)&Vs[0][0] + (w * 64 + i * 256) * 16);
    }
    asm volatile("s_waitcnt vmcnt(0)" ::: "memory");
    __syncthreads();

    for (int st = 0; st <= tq; ++st) {
        const int cur = st & 1;
        if (st < tq) {  // prefetch next tile into the other buffer
            const int nx = cur ^ 1;
#pragma unroll
            for (int i = 0; i < 2; ++i) {
                const int slot = w * 64 + i * 256 + lane;
                const int row = slot >> 3, cb = slot & 7;
                const int cbs = cb ^ (row & 7);
                gll16(Kg + base + (size_t)((st + 1) * 64 + row) * Dc + cbs * 8,
                      (char*)&Ks[nx][0] + (w * 64 + i * 256) * 16);
                gll16(Vtg + base + (size_t)row * Tc + (st + 1) * 64 + cbs * 8,
                      (char*)&Vs[nx][0] + (w * 64 + i * 256) * 16);
            }
        }

        // S^T = K·Q : lane holds q=l15, key = fn*16 + l4*4 + r (log2 space)
        const char* Kc = (const char*)&Ks[cur][0];
        const char* Vc = (const char*)&Vs[cur][0];
        f32x4 s[4];
#pragma unroll
        for (int fn = 0; fn < 4; ++fn) s[fn] = (f32x4)0.f;
        __builtin_amdgcn_s_setprio(1);
#pragma unroll
        for (int kf = 0; kf < 2; ++kf)
#pragma unroll
            for (int fn = 0; fn < 4; ++fn) {
                const int srow = fn * 16 + l15;   // key row in K tile
                bf16x8 kb = *(const bf16x8*)(Kc + srow * 128 +
                                             ((kf * 64 + l4 * 16) ^ ((srow & 7) << 4)));
                s[fn] = __builtin_amdgcn_mfma_f32_16x16x32_bf16(kb, qf[kf], s[fn], 0, 0, 0);
            }
        __builtin_amdgcn_s_setprio(0);

        if (st == tq) {  // causal mask: key > q  (tile-local indices)
#pragma unroll
            for (int fn = 0; fn < 4; ++fn)
#pragma unroll
                for (int r = 0; r < 4; ++r)
                    if (fn * 16 + l4 * 4 + r > w * 16 + l15) s[fn][r] = -1e30f;
        }

        // online softmax (log2 space), per-lane q = l15
        float tm = -1e30f;
#pragma unroll
        for (int fn = 0; fn < 4; ++fn)
#pragma unroll
            for (int r = 0; r < 4; ++r) tm = fmaxf(tm, s[fn][r]);
        tm = fmaxf(tm, __shfl_xor(tm, 16));
        tm = fmaxf(tm, __shfl_xor(tm, 32));
        // T13 defer-max: only rescale when some row's max grew past THR=8
        if (!__all(tm - mr <= 8.0f)) {
            const float mn = fmaxf(mr, tm);
            const float alpha = __builtin_amdgcn_exp2f(mr - mn);
            mr = mn;
            ls *= alpha;
#pragma unroll
            for (int fd = 0; fd < 4; ++fd)
#pragma unroll
                for (int r = 0; r < 4; ++r) ot[fd][r] *= alpha;
        }
        float rs = 0.f;
#pragma unroll
        for (int fn = 0; fn < 4; ++fn)
#pragma unroll
            for (int r = 0; r < 4; ++r) {
                const float p = __builtin_amdgcn_exp2f(s[fn][r] - mr);
                s[fn][r] = p;
                rs += p;
            }
        rs += __shfl_xor(rs, 16);
        rs += __shfl_xor(rs, 32);
        ls += rs;

        // pack P to bf16 quads via v_cvt_pk_bf16_f32 (T12)
        unsigned long long plo[4];
#pragma unroll
        for (int fn = 0; fn < 4; ++fn) {
            unsigned pk0, pk1;
            asm("v_cvt_pk_bf16_f32 %0, %1, %2" : "=v"(pk0) : "v"(s[fn][0]), "v"(s[fn][1]));
            asm("v_cvt_pk_bf16_f32 %0, %1, %2" : "=v"(pk1) : "v"(s[fn][2]), "v"(s[fn][3]));
            plo[fn] = (unsigned long long)pk0 | ((unsigned long long)pk1 << 32);
        }

        // build PV B-fragments by shuffle exchange:
        // pb[kf] elem e <-> key k = kf*32 + l4*8 + e
        bf16x8 pb[2];
#pragma unroll
        for (int kf = 0; kf < 2; ++kf) {
            unsigned long long a0 = __shfl(plo[kf * 2],     srcA, 64);
            unsigned long long a1 = __shfl(plo[kf * 2 + 1], srcA, 64);
            unsigned long long b0 = __shfl(plo[kf * 2],     srcB, 64);
            unsigned long long b1 = __shfl(plo[kf * 2 + 1], srcB, 64);
            union { unsigned long long u[2]; bf16x8 v; } cvt;
            cvt.u[0] = hiFn ? a1 : a0;
            cvt.u[1] = hiFn ? b1 : b0;
            pb[kf] = cvt.v;
        }

        // O^T += Vt · P^T
        __builtin_amdgcn_s_setprio(1);
#pragma unroll
        for (int kf = 0; kf < 2; ++kf)
#pragma unroll
            for (int fd = 0; fd < 4; ++fd) {
                const int vrow = fd * 16 + l15;   // d row in Vt tile
                bf16x8 vb = *(const bf16x8*)(Vc + vrow * 128 +
                                             ((kf * 64 + l4 * 16) ^ ((vrow & 7) << 4)));
                ot[fd] = __builtin_amdgcn_mfma_f32_16x16x32_bf16(vb, pb[kf], ot[fd], 0, 0, 0);
            }
        __builtin_amdgcn_s_setprio(0);

        if (st < tq) {
            asm volatile("s_waitcnt vmcnt(0)" ::: "memory");
            __syncthreads();
        }
    }

    // normalize + store: row q = q0 + l15, cols d = fd*16 + l4*4 + 0..3
    const float inv = 1.f / ls;
    const size_t rowb = (size_t)(b * Tc + q0 + l15) * Ec + h * Dc;
#pragma unroll
    for (int fd = 0; fd < 4; ++fd) {
        short4 r4;
        r4.x = f2b(ot[fd][0] * inv);
        r4.y = f2b(ot[fd][1] * inv);
        r4.z = f2b(ot[fd][2] * inv);
        r4.w = f2b(ot[fd][3] * inv);
        *(short4*)(Ab + rowb + fd * 16 + l4 * 4) = r4;
    }
}

// ---------------------------------------------------------------------------
extern "C" void kernel_launch(void* const* d_in, const int* in_sizes, int n_in,
                              void* d_out, int out_size, void* d_ws, size_t ws_size,
                              hipStream_t stream)
{
    const float* x     = (const float*)d_in[0];
    const float* w_qkv = (const float*)d_in[1];
    const float* b_qkv = (const float*)d_in[2];
    const float* w_out = (const float*)d_in[3];
    const float* b_out = (const float*)d_in[4];
    float* out = (float*)d_out;

    const size_t NX = (size_t)8192 * 1024;
    short* xb  = (short*)d_ws;        // 16 MB
    short* Wtq = xb + NX;             // [3072][1024] bf16
    short* Wto = Wtq + (size_t)3072 * 1024;  // [1024][1024] bf16
    short* Qb  = Wto + (size_t)1024 * 1024;  // [B,H,T,D] bf16
    short* Kb  = Qb + NX;
    short* Vt  = Kb + NX;             // [B,H,D,T] bf16
    short* Ab  = Vt + NX;             // [B*T][E] bf16

    convert_f32_bf16<<<8192, 256, 0, stream>>>(x, xb, (int)NX);
    transpose_conv<<<dim3(48, 16), 256, 0, stream>>>(w_qkv, Wtq, 1024, 3072);
    transpose_conv<<<dim3(16, 16), 256, 0, stream>>>(w_out, Wto, 1024, 1024);

    gemm_bf16<0><<<dim3(24, 64), 256, 0, stream>>>(
        xb, Wtq, b_qkv, Qb, Kb, Vt, nullptr, 8192, 3072, 1024);

    attn_mfma5<<<2048, 256, 0, stream>>>(Qb, Kb, Vt, Ab);

    gemm_bf16<1><<<dim3(8, 64), 256, 0, stream>>>(
        Ab, Wto, b_out, nullptr, nullptr, nullptr, out, 8192, 1024, 1024);
}